// Round 2
// 371.955 us; speedup vs baseline: 1.0114x; 1.0114x over previous
//
#include <hip/hip_runtime.h>

// DepenL: 3x3 unfold (pad=1, stride=1) of key/query [4,64,128,128] fp32.
// The torch-style .view of [B, C*kk, L] as [B, C, L, kk] is a raw row-major
// reinterpretation: within a (b,c) plane of 9*16384 elements, output flat
// index n corresponds to unfold element (p = n>>14, l = n&16383). The
// "center" slice element (i, j=4) sits at flat index 9*i+4, whose unfold
// coords are p=(9i+4)>>14, l=(9i+4)&16383 — NOT the unfold-center patch.
// out1[n] = U_key[n] * C_qry(n/9);  out2[n] = C_key(n/9) * U_qry[n].
//
// R4 = R3 with the nontemporal-store compile fix (native ext_vector float4,
// not HIP_vector_type). Changes vs the 376us kernel (compute core untouched):
//  1. 1D grid + XCD-affinity swizzle: blocks round-robin XCDs (b%8); remap
//     so each XCD owns a contiguous slab of 32 planes -> each 64KB input
//     plane is fetched into exactly ONE XCD L2 instead of all 8 (kills the
//     ~8x HBM read amplification of the (144,256) grid).
//  2. Non-temporal stores for the 302MB out1/out2 stream -> no L2 thrash of
//     the hot, re-read input planes.

#define LPP   16384     // 128*128 pixels per plane
#define NPP   147456    // 9*LPP output elements per plane per array
#define HW    128

typedef float v4f __attribute__((ext_vector_type(4)));

__device__ __forceinline__ int unfold_off(int n, bool& valid) {
    // input-plane offset for unfold flat index n; valid=false -> value is 0
    const int p  = n >> 14;
    const int l  = n & (LPP - 1);
    const int ho = l >> 7;
    const int wo = l & (HW - 1);
    const int ki = p / 3;
    const int kj = p - 3 * ki;
    const int h  = ho + ki - 1;
    const int w  = wo + kj - 1;
    valid = ((unsigned)h < (unsigned)HW) && ((unsigned)w < (unsigned)HW);
    return h * HW + w;
}

extern "C" __global__ __launch_bounds__(256) void depen_kernel(
    const float* __restrict__ key, const float* __restrict__ qry,
    float* __restrict__ out1, float* __restrict__ out2)
{
    // ---- XCD-affinity swizzle ----
    // 36864 blocks total; XCD = b%8 (round-robin dispatch). u enumerates
    // work-units contiguously PER XCD: XCD k gets planes [32k, 32k+32).
    const int b  = blockIdx.x;                   // 0..36863
    const int u  = (b & 7) * 4608 + (b >> 3);    // 4608 = 36864/8, bijective
    const int bc = u / 144;                      // plane 0..255 (b*C+c)
    const int xb = u - 144 * bc;                 // 0..143 within plane

    const int n0 = 4 * (xb * 256 + (int)threadIdx.x);   // mult of 4

    const float* __restrict__ kp = key + (size_t)bc * LPP;
    const float* __restrict__ qp = qry + (size_t)bc * LPP;

    // ---- 4 unfold values (same p, same input row for all 4) ----
    const int p   = n0 >> 14;            // uniform per block (1024 | 16384)
    const int l0  = n0 & (LPP - 1);
    const int ho  = l0 >> 7;
    const int wo0 = l0 & (HW - 1);       // multiple of 4
    const int ki  = p / 3;
    const int kj  = p - 3 * ki;
    const int h   = ho + ki - 1;

    float kv[4], qv[4];
    if ((unsigned)h < (unsigned)HW) {
        const int base = h * HW + wo0 + kj - 1;   // w = wo0+kj-1+e
        kv[1] = kp[base + 1];  qv[1] = qp[base + 1];   // always in-bounds
        kv[2] = kp[base + 2];  qv[2] = qp[base + 2];
        const bool v0 = (wo0 + kj) > 0;           // fails only wo0=0,  kj=0
        const bool v3 = (wo0 + kj + 2) < HW;      // fails only wo0=124,kj=2
        kv[0] = v0 ? kp[base]     : 0.0f;
        qv[0] = v0 ? qp[base]     : 0.0f;
        kv[3] = v3 ? kp[base + 3] : 0.0f;
        qv[3] = v3 ? qp[base + 3] : 0.0f;
    } else {
        kv[0]=kv[1]=kv[2]=kv[3]=0.0f;
        qv[0]=qv[1]=qv[2]=qv[3]=0.0f;
    }

    // ---- centers: at most 2 distinct i across 4 consecutive n ----
    const int i0 = n0 / 9;
    const int r  = n0 - 9 * i0;          // 0..8
    const int i1 = (n0 + 3) / 9;         // i0 or i0+1, always < 16384

    bool va, vb;
    const int offa = unfold_off(9 * i0 + 4, va);
    const int offb = unfold_off(9 * i1 + 4, vb);
    const float ck0 = va ? kp[offa] : 0.0f;
    const float cq0 = va ? qp[offa] : 0.0f;
    const float ck1 = vb ? kp[offb] : 0.0f;
    const float cq1 = vb ? qp[offb] : 0.0f;

    // ---- compute + fully-coalesced nontemporal float4 stores ----
    float o1[4], o2[4];
    #pragma unroll
    for (int e = 0; e < 4; ++e) {
        const bool first = (r + e) < 9;
        const float cq = first ? cq0 : cq1;
        const float ck = first ? ck0 : ck1;
        o1[e] = kv[e] * cq;
        o2[e] = ck * qv[e];
    }

    const size_t ob = (size_t)bc * NPP + n0;
    v4f w1; w1.x = o1[0]; w1.y = o1[1]; w1.z = o1[2]; w1.w = o1[3];
    v4f w2; w2.x = o2[0]; w2.y = o2[1]; w2.z = o2[2]; w2.w = o2[3];
    __builtin_nontemporal_store(w1, reinterpret_cast<v4f*>(out1 + ob));
    __builtin_nontemporal_store(w2, reinterpret_cast<v4f*>(out2 + ob));
}

extern "C" void kernel_launch(void* const* d_in, const int* in_sizes, int n_in,
                              void* d_out, int out_size, void* d_ws, size_t ws_size,
                              hipStream_t stream) {
    const float* key = (const float*)d_in[0];   // key_map   [4,64,128,128]
    const float* qry = (const float*)d_in[1];   // query_map [4,64,128,128]
    float* out1 = (float*)d_out;                // [4,64,16384,9]
    float* out2 = out1 + (size_t)256 * NPP;     // second tuple element

    // 256 planes (B*C) x 144 blocks/plane = 36864 blocks of 256 threads
    dim3 grid(36864, 1, 1);
    dim3 block(256, 1, 1);
    depen_kernel<<<grid, block, 0, stream>>>(key, qry, out1, out2);
}

// Round 3
// 357.564 us; speedup vs baseline: 1.0521x; 1.0402x over previous
//
#include <hip/hip_runtime.h>

// DepenL: 3x3 unfold (pad=1, stride=1) of key/query [4,64,128,128] fp32.
// The torch-style .view of [B, C*kk, L] as [B, C, L, kk] is a raw row-major
// reinterpretation: within a (b,c) plane of 9*16384 elements, output flat
// index n corresponds to unfold element (p = n>>14, l = n&16383). The
// "center" slice element (i, j=4) sits at flat index 9*i+4, whose unfold
// coords are p=(9i+4)>>14, l=(9i+4)&16383 — NOT the unfold-center patch.
// out1[n] = U_key[n] * C_qry(n/9);  out2[n] = C_key(n/9) * U_qry[n].
//
// R5: widen to 8 outputs/thread per array (was 4). Rationale: R3/R4's
// locality levers (XCD swizzle, nt stores) were NULL -> inputs are
// L3-resident and the kernel (~182us vs ~60us write-roofline) is in-core
// bound: per-thread VMEM count + /9 and /3 integer-division chains.
// 8 consecutive n still span <=2 centers (8<9) and share one patch p
// (n0 multiple of 8, p-slab = 16384), so ALL per-thread fixed work
// amortizes over 2x outputs; wave count halves.
//  - e=1..6 always in-bounds (given h valid); e=0 invalid only wo0=0,kj=0;
//    e=7 invalid only wo0=120,kj=2.  (verified boundary structure)

#define LPP   16384     // 128*128 pixels per plane
#define NPP   147456    // 9*LPP output elements per plane per array
#define HW    128

typedef float v4f __attribute__((ext_vector_type(4)));

__device__ __forceinline__ int unfold_off(int n, bool& valid) {
    // input-plane offset for unfold flat index n; valid=false -> value is 0
    const int p  = n >> 14;
    const int l  = n & (LPP - 1);
    const int ho = l >> 7;
    const int wo = l & (HW - 1);
    const int ki = p / 3;
    const int kj = p - 3 * ki;
    const int h  = ho + ki - 1;
    const int w  = wo + kj - 1;
    valid = ((unsigned)h < (unsigned)HW) && ((unsigned)w < (unsigned)HW);
    return h * HW + w;
}

extern "C" __global__ __launch_bounds__(256) void depen_kernel(
    const float* __restrict__ key, const float* __restrict__ qry,
    float* __restrict__ out1, float* __restrict__ out2)
{
    // ---- XCD-affinity swizzle (neutral but harmless; keeps L2 locality) ----
    // 18432 blocks; XCD = b%8. u enumerates work contiguously per XCD.
    const int b  = blockIdx.x;                   // 0..18431
    const int u  = (b & 7) * 2304 + (b >> 3);    // 2304 = 18432/8, bijective
    const int bc = u / 72;                       // plane 0..255 (b*C+c)
    const int xb = u - 72 * bc;                  // 0..71 within plane

    const int n0 = 8 * (xb * 256 + (int)threadIdx.x);   // mult of 8

    const float* __restrict__ kp = key + (size_t)bc * LPP;
    const float* __restrict__ qp = qry + (size_t)bc * LPP;

    // ---- 8 unfold values: same p, same input row for all 8 ----
    const int p   = n0 >> 14;            // uniform per block (2048 | 16384)
    const int l0  = n0 & (LPP - 1);
    const int ho  = l0 >> 7;
    const int wo0 = l0 & (HW - 1);       // multiple of 8, 0..120
    const int ki  = p / 3;
    const int kj  = p - 3 * ki;
    const int h   = ho + ki - 1;

    float kv[8], qv[8];
    if ((unsigned)h < (unsigned)HW) {
        const int base = h * HW + wo0 + kj - 1;   // w = wo0+kj-1+e
        #pragma unroll
        for (int e = 1; e <= 6; ++e) {            // always in-bounds
            kv[e] = kp[base + e];
            qv[e] = qp[base + e];
        }
        const bool v0 = (wo0 + kj) > 0;           // fails only wo0=0,  kj=0
        const bool v7 = (wo0 + kj) < 122;         // fails only wo0=120,kj=2
        kv[0] = v0 ? kp[base]     : 0.0f;
        qv[0] = v0 ? qp[base]     : 0.0f;
        kv[7] = v7 ? kp[base + 7] : 0.0f;
        qv[7] = v7 ? qp[base + 7] : 0.0f;
    } else {
        #pragma unroll
        for (int e = 0; e < 8; ++e) { kv[e] = 0.0f; qv[e] = 0.0f; }
    }

    // ---- centers: at most 2 distinct i across 8 consecutive n (8 < 9) ----
    const int i0 = n0 / 9;
    const int r  = n0 - 9 * i0;          // 0..8
    const int i1 = (n0 + 7) / 9;         // i0 or i0+1, always < 16384

    bool va, vb;
    const int offa = unfold_off(9 * i0 + 4, va);
    const int offb = unfold_off(9 * i1 + 4, vb);
    const float ck0 = va ? kp[offa] : 0.0f;
    const float cq0 = va ? qp[offa] : 0.0f;
    const float ck1 = vb ? kp[offb] : 0.0f;
    const float cq1 = vb ? qp[offb] : 0.0f;

    // ---- compute + fully-coalesced 2x float4 nt stores per array ----
    const size_t ob = (size_t)bc * NPP + n0;     // 32B-aligned

    float o[8];
    #pragma unroll
    for (int e = 0; e < 8; ++e)
        o[e] = kv[e] * (((r + e) < 9) ? cq0 : cq1);
    {
        v4f w0; w0.x=o[0]; w0.y=o[1]; w0.z=o[2]; w0.w=o[3];
        v4f w1; w1.x=o[4]; w1.y=o[5]; w1.z=o[6]; w1.w=o[7];
        __builtin_nontemporal_store(w0, reinterpret_cast<v4f*>(out1 + ob));
        __builtin_nontemporal_store(w1, reinterpret_cast<v4f*>(out1 + ob + 4));
    }
    #pragma unroll
    for (int e = 0; e < 8; ++e)
        o[e] = (((r + e) < 9) ? ck0 : ck1) * qv[e];
    {
        v4f w0; w0.x=o[0]; w0.y=o[1]; w0.z=o[2]; w0.w=o[3];
        v4f w1; w1.x=o[4]; w1.y=o[5]; w1.z=o[6]; w1.w=o[7];
        __builtin_nontemporal_store(w0, reinterpret_cast<v4f*>(out2 + ob));
        __builtin_nontemporal_store(w1, reinterpret_cast<v4f*>(out2 + ob + 4));
    }
}

extern "C" void kernel_launch(void* const* d_in, const int* in_sizes, int n_in,
                              void* d_out, int out_size, void* d_ws, size_t ws_size,
                              hipStream_t stream) {
    const float* key = (const float*)d_in[0];   // key_map   [4,64,128,128]
    const float* qry = (const float*)d_in[1];   // query_map [4,64,128,128]
    float* out1 = (float*)d_out;                // [4,64,16384,9]
    float* out2 = out1 + (size_t)256 * NPP;     // second tuple element

    // 256 planes (B*C) x 72 blocks/plane = 18432 blocks of 256 threads,
    // 8 outputs/thread/array
    dim3 grid(18432, 1, 1);
    dim3 block(256, 1, 1);
    depen_kernel<<<grid, block, 0, stream>>>(key, qry, out1, out2);
}

// Round 4
// 352.843 us; speedup vs baseline: 1.0662x; 1.0134x over previous
//
#include <hip/hip_runtime.h>

// DepenL: 3x3 unfold (pad=1, stride=1) of key/query [4,64,128,128] fp32.
// out flat n within plane = unfold flat (p = n>>14, l = n&16383); the
// "center" factor for n is input[unfold_off(9*(n/9)+4)].
// out1[n] = U_key[n] * C_qry(n/9);  out2[n] = C_key(n/9) * U_qry[n].
//
// R6: vectorized unfold loads. R5's 16 scalar unfold loads (misaligned by
// kj-1) were the VMEM/L1-line bottleneck (each instr: 32 lines for 256B
// useful). Replace with 2x dwordx4 per array on the ALIGNED window
// [wo0,wo0+8) + one cross-lane __shfl for the single out-of-window element.
// The shuffle's row-boundary-crossing cases (wo0=0&kj=0, wo0=120&kj=2) are
// exactly the cases the boundary masks already zero -> no patch loads.
// kj is block-uniform (2048 n's per block, p-slab 16384) -> no divergence.
// VMEM/thread: 24 -> 12. Compute & center logic unchanged (absmax was 0).

#define LPP   16384     // 128*128 pixels per plane
#define NPP   147456    // 9*LPP output elements per plane per array
#define HW    128

typedef float v4f __attribute__((ext_vector_type(4)));

__device__ __forceinline__ int unfold_off(int n, bool& valid) {
    // input-plane offset for unfold flat index n; valid=false -> value is 0
    const int p  = n >> 14;
    const int l  = n & (LPP - 1);
    const int ho = l >> 7;
    const int wo = l & (HW - 1);
    const int ki = p / 3;
    const int kj = p - 3 * ki;
    const int h  = ho + ki - 1;
    const int w  = wo + kj - 1;
    valid = ((unsigned)h < (unsigned)HW) && ((unsigned)w < (unsigned)HW);
    return h * HW + w;
}

extern "C" __global__ __launch_bounds__(256) void depen_kernel(
    const float* __restrict__ key, const float* __restrict__ qry,
    float* __restrict__ out1, float* __restrict__ out2)
{
    // ---- XCD-affinity swizzle (neutral but harmless) ----
    const int b  = blockIdx.x;                   // 0..18431
    const int u  = (b & 7) * 2304 + (b >> 3);    // bijective
    const int bc = u / 72;                       // plane 0..255
    const int xb = u - 72 * bc;                  // 0..71 within plane

    const int n0 = 8 * (xb * 256 + (int)threadIdx.x);   // mult of 8

    const float* __restrict__ kp = key + (size_t)bc * LPP;
    const float* __restrict__ qp = qry + (size_t)bc * LPP;

    // ---- decode (p uniform per block) ----
    const int p   = n0 >> 14;
    const int l0  = n0 & (LPP - 1);
    const int ho  = l0 >> 7;
    const int wo0 = l0 & (HW - 1);       // multiple of 8, 0..120
    const int ki  = p / 3;
    const int kj  = p - 3 * ki;
    const int h   = ho + ki - 1;
    const bool hok = (unsigned)h < (unsigned)HW;
    const int hc  = hok ? h : (h < 0 ? 0 : HW - 1);   // clamped (safe) row
    const int base = hc * HW + wo0;                   // 32B-aligned

    // ---- aligned window [wo0, wo0+8): 2x dwordx4 per array ----
    const v4f klo = *reinterpret_cast<const v4f*>(kp + base);
    const v4f khi = *reinterpret_cast<const v4f*>(kp + base + 4);
    const v4f qlo = *reinterpret_cast<const v4f*>(qp + base);
    const v4f qhi = *reinterpret_cast<const v4f*>(qp + base + 4);

    float kw[8] = {klo[0],klo[1],klo[2],klo[3],khi[0],khi[1],khi[2],khi[3]};
    float qw[8] = {qlo[0],qlo[1],qlo[2],qlo[3],qhi[0],qhi[1],qhi[2],qhi[3]};

    // ---- shift to needed window [wo0+kj-1, wo0+kj+7) via 1 shfl ----
    // Lane layout: 16 lanes per row (wo0 = 0,8,...,120). The shuffle only
    // crosses a row boundary when the result is masked to 0 anyway.
    float kv[8], qv[8];
    if (kj == 1) {                       // aligned: w = wo0+e, always valid
        #pragma unroll
        for (int e = 0; e < 8; ++e) { kv[e] = kw[e]; qv[e] = qw[e]; }
    } else if (kj == 0) {                // w = wo0-1+e
        const float kprev = __shfl_up(kw[7], 1);   // prev lane's elem 7
        const float qprev = __shfl_up(qw[7], 1);
        kv[0] = (wo0 > 0) ? kprev : 0.0f;          // wo0==0 -> w=-1 -> 0
        qv[0] = (wo0 > 0) ? qprev : 0.0f;
        #pragma unroll
        for (int e = 1; e < 8; ++e) { kv[e] = kw[e-1]; qv[e] = qw[e-1]; }
    } else {                             // kj==2: w = wo0+1+e
        const float knext = __shfl_down(kw[0], 1); // next lane's elem 0
        const float qnext = __shfl_down(qw[0], 1);
        #pragma unroll
        for (int e = 0; e < 7; ++e) { kv[e] = kw[e+1]; qv[e] = qw[e+1]; }
        kv[7] = (wo0 < 120) ? knext : 0.0f;        // wo0==120 -> w=128 -> 0
        qv[7] = (wo0 < 120) ? qnext : 0.0f;
    }
    if (!hok) {                          // whole row out of bounds
        #pragma unroll
        for (int e = 0; e < 8; ++e) { kv[e] = 0.0f; qv[e] = 0.0f; }
    }

    // ---- centers: at most 2 distinct i across 8 consecutive n (8 < 9) ----
    const int i0 = n0 / 9;
    const int r  = n0 - 9 * i0;          // 0..8
    const int i1 = (n0 + 7) / 9;         // i0 or i0+1, always < 16384

    bool va, vb;
    const int offa = unfold_off(9 * i0 + 4, va);
    const int offb = unfold_off(9 * i1 + 4, vb);
    const float ck0 = va ? kp[offa] : 0.0f;
    const float cq0 = va ? qp[offa] : 0.0f;
    const float ck1 = vb ? kp[offb] : 0.0f;
    const float cq1 = vb ? qp[offb] : 0.0f;

    // ---- compute + fully-coalesced 2x float4 nt stores per array ----
    const size_t ob = (size_t)bc * NPP + n0;     // 32B-aligned

    float o[8];
    #pragma unroll
    for (int e = 0; e < 8; ++e)
        o[e] = kv[e] * (((r + e) < 9) ? cq0 : cq1);
    {
        v4f w0; w0[0]=o[0]; w0[1]=o[1]; w0[2]=o[2]; w0[3]=o[3];
        v4f w1; w1[0]=o[4]; w1[1]=o[5]; w1[2]=o[6]; w1[3]=o[7];
        __builtin_nontemporal_store(w0, reinterpret_cast<v4f*>(out1 + ob));
        __builtin_nontemporal_store(w1, reinterpret_cast<v4f*>(out1 + ob + 4));
    }
    #pragma unroll
    for (int e = 0; e < 8; ++e)
        o[e] = (((r + e) < 9) ? ck0 : ck1) * qv[e];
    {
        v4f w0; w0[0]=o[0]; w0[1]=o[1]; w0[2]=o[2]; w0[3]=o[3];
        v4f w1; w1[0]=o[4]; w1[1]=o[5]; w1[2]=o[6]; w1[3]=o[7];
        __builtin_nontemporal_store(w0, reinterpret_cast<v4f*>(out2 + ob));
        __builtin_nontemporal_store(w1, reinterpret_cast<v4f*>(out2 + ob + 4));
    }
}

extern "C" void kernel_launch(void* const* d_in, const int* in_sizes, int n_in,
                              void* d_out, int out_size, void* d_ws, size_t ws_size,
                              hipStream_t stream) {
    const float* key = (const float*)d_in[0];   // key_map   [4,64,128,128]
    const float* qry = (const float*)d_in[1];   // query_map [4,64,128,128]
    float* out1 = (float*)d_out;                // [4,64,16384,9]
    float* out2 = out1 + (size_t)256 * NPP;     // second tuple element

    // 256 planes (B*C) x 72 blocks/plane = 18432 blocks of 256 threads,
    // 8 outputs/thread/array
    dim3 grid(18432, 1, 1);
    dim3 block(256, 1, 1);
    depen_kernel<<<grid, block, 0, stream>>>(key, qry, out1, out2);
}

// Round 5
// 335.833 us; speedup vs baseline: 1.1202x; 1.0506x over previous
//
#include <hip/hip_runtime.h>

// DepenL: 3x3 unfold (pad=1, stride=1) of key/query [4,64,128,128] fp32.
// out flat n within plane = unfold flat (p = n>>14, l = n&16383); the
// "center" factor for n is input[unfold_off(9*(n/9)+4)].
// out1[n] = U_key[n] * C_qry(n/9);  out2[n] = C_key(n/9) * U_qry[n].
//
// R7 (on top of R6's vectorized window loads + shfl shift, absmax 0):
//  1. Cooperative wave centers: a wave needs C(i) for ~58 CONSECUTIVE i.
//     Lane L loads C(i_base+L) once (2 gathers/thread, was 4; 1 unfold_off
//     decode, was 2) and threads fetch their ck0/cq0/ck1/cq1 via __shfl
//     (idx = i0-i_base <= 57, i1-i_base <= 58 -- always in-wave).
//     Out-of-range lanes decode safely: invalid -> masked to 0, and valid
//     garbage (m > 16383) is never selected by any idx.
//  2. Scalar-hoisted decode: blocks are 2048-aligned in n, 16384%2048==0,
//     so p = xb>>3 (SALU), ki=p/3, kj uniform (branch provably uniform),
//     ho = 16*(xb&7)+(tid>>4), wo0 = 8*(tid&15). ~20 VALU -> SALU.

#define LPP   16384     // 128*128 pixels per plane
#define NPP   147456    // 9*LPP output elements per plane per array
#define HW    128

typedef float v4f __attribute__((ext_vector_type(4)));

__device__ __forceinline__ int unfold_off(int n, bool& valid) {
    // input-plane offset for unfold flat index n; valid=false -> value is 0
    const int p  = n >> 14;
    const int l  = n & (LPP - 1);
    const int ho = l >> 7;
    const int wo = l & (HW - 1);
    const int ki = p / 3;
    const int kj = p - 3 * ki;
    const int h  = ho + ki - 1;
    const int w  = wo + kj - 1;
    valid = ((unsigned)h < (unsigned)HW) && ((unsigned)w < (unsigned)HW);
    return h * HW + w;
}

extern "C" __global__ __launch_bounds__(256) void depen_kernel(
    const float* __restrict__ key, const float* __restrict__ qry,
    float* __restrict__ out1, float* __restrict__ out2)
{
    // ---- XCD-affinity swizzle (neutral but harmless) ----
    const int b  = blockIdx.x;                   // 0..18431
    const int u  = (b & 7) * 2304 + (b >> 3);    // bijective
    const int bc = u / 72;                       // plane 0..255
    const int xb = u - 72 * bc;                  // 0..71 within plane

    const int tid = threadIdx.x;
    const int n0  = (xb << 11) + (tid << 3);     // mult of 8, in-plane flat

    const float* __restrict__ kp = key + (size_t)bc * LPP;
    const float* __restrict__ qp = qry + (size_t)bc * LPP;

    // ---- scalar-hoisted decode (block spans exactly 2048 n's, aligned) ----
    const int p   = xb >> 3;                     // SALU, uniform
    const int ki  = p / 3;                       // SALU
    const int kj  = p - 3 * ki;                  // SALU, uniform branch key
    const int ho  = ((xb & 7) << 4) + (tid >> 4);
    const int wo0 = (tid & 15) << 3;             // multiple of 8, 0..120
    const int h   = ho + ki - 1;
    const bool hok = (unsigned)h < (unsigned)HW;
    const int hc  = hok ? h : (h < 0 ? 0 : HW - 1);   // clamped (safe) row
    const int base = hc * HW + wo0;                   // 32B-aligned

    // ---- aligned window [wo0, wo0+8): 2x dwordx4 per array ----
    const v4f klo = *reinterpret_cast<const v4f*>(kp + base);
    const v4f khi = *reinterpret_cast<const v4f*>(kp + base + 4);
    const v4f qlo = *reinterpret_cast<const v4f*>(qp + base);
    const v4f qhi = *reinterpret_cast<const v4f*>(qp + base + 4);

    float kw[8] = {klo[0],klo[1],klo[2],klo[3],khi[0],khi[1],khi[2],khi[3]};
    float qw[8] = {qlo[0],qlo[1],qlo[2],qlo[3],qhi[0],qhi[1],qhi[2],qhi[3]};

    // ---- cooperative centers: lane L covers i = i_base + L ----
    const int i0 = n0 / 9;
    const int r  = n0 - 9 * i0;          // 0..8
    const int i1 = (n0 + 7) / 9;         // i0 or i0+1

    const int lane   = tid & 63;
    const int i_base = __builtin_amdgcn_readfirstlane(i0);
    bool vm;
    const int offm = unfold_off(9 * (i_base + lane) + 4, vm);
    const float ckL = vm ? kp[offm] : 0.0f;
    const float cqL = vm ? qp[offm] : 0.0f;
    const int idx0 = i0 - i_base;        // 0..57, always in-wave
    const int idx1 = i1 - i_base;        // 0..58, always in-wave
    const float ck0 = __shfl(ckL, idx0);
    const float cq0 = __shfl(cqL, idx0);
    const float ck1 = __shfl(ckL, idx1);
    const float cq1 = __shfl(cqL, idx1);

    // ---- shift to needed window [wo0+kj-1, wo0+kj+7) via 1 shfl ----
    // 16 lanes per row (wo0 = 0..120 step 8). The shuffle only crosses a
    // row boundary when the result is masked to 0 anyway.
    float kv[8], qv[8];
    if (kj == 1) {                       // aligned: w = wo0+e, always valid
        #pragma unroll
        for (int e = 0; e < 8; ++e) { kv[e] = kw[e]; qv[e] = qw[e]; }
    } else if (kj == 0) {                // w = wo0-1+e
        const float kprev = __shfl_up(kw[7], 1);   // prev lane's elem 7
        const float qprev = __shfl_up(qw[7], 1);
        kv[0] = (wo0 > 0) ? kprev : 0.0f;          // wo0==0 -> w=-1 -> 0
        qv[0] = (wo0 > 0) ? qprev : 0.0f;
        #pragma unroll
        for (int e = 1; e < 8; ++e) { kv[e] = kw[e-1]; qv[e] = qw[e-1]; }
    } else {                             // kj==2: w = wo0+1+e
        const float knext = __shfl_down(kw[0], 1); // next lane's elem 0
        const float qnext = __shfl_down(qw[0], 1);
        #pragma unroll
        for (int e = 0; e < 7; ++e) { kv[e] = kw[e+1]; qv[e] = qw[e+1]; }
        kv[7] = (wo0 < 120) ? knext : 0.0f;        // wo0==120 -> w=128 -> 0
        qv[7] = (wo0 < 120) ? qnext : 0.0f;
    }
    if (!hok) {                          // whole row out of bounds
        #pragma unroll
        for (int e = 0; e < 8; ++e) { kv[e] = 0.0f; qv[e] = 0.0f; }
    }

    // ---- compute + fully-coalesced 2x float4 nt stores per array ----
    const size_t ob = (size_t)bc * NPP + n0;     // 32B-aligned

    float o[8];
    #pragma unroll
    for (int e = 0; e < 8; ++e)
        o[e] = kv[e] * (((r + e) < 9) ? cq0 : cq1);
    {
        v4f w0; w0[0]=o[0]; w0[1]=o[1]; w0[2]=o[2]; w0[3]=o[3];
        v4f w1; w1[0]=o[4]; w1[1]=o[5]; w1[2]=o[6]; w1[3]=o[7];
        __builtin_nontemporal_store(w0, reinterpret_cast<v4f*>(out1 + ob));
        __builtin_nontemporal_store(w1, reinterpret_cast<v4f*>(out1 + ob + 4));
    }
    #pragma unroll
    for (int e = 0; e < 8; ++e)
        o[e] = (((r + e) < 9) ? ck0 : ck1) * qv[e];
    {
        v4f w0; w0[0]=o[0]; w0[1]=o[1]; w0[2]=o[2]; w0[3]=o[3];
        v4f w1; w1[0]=o[4]; w1[1]=o[5]; w1[2]=o[6]; w1[3]=o[7];
        __builtin_nontemporal_store(w0, reinterpret_cast<v4f*>(out2 + ob));
        __builtin_nontemporal_store(w1, reinterpret_cast<v4f*>(out2 + ob + 4));
    }
}

extern "C" void kernel_launch(void* const* d_in, const int* in_sizes, int n_in,
                              void* d_out, int out_size, void* d_ws, size_t ws_size,
                              hipStream_t stream) {
    const float* key = (const float*)d_in[0];   // key_map   [4,64,128,128]
    const float* qry = (const float*)d_in[1];   // query_map [4,64,128,128]
    float* out1 = (float*)d_out;                // [4,64,16384,9]
    float* out2 = out1 + (size_t)256 * NPP;     // second tuple element

    // 256 planes (B*C) x 72 blocks/plane = 18432 blocks of 256 threads,
    // 8 outputs/thread/array
    dim3 grid(18432, 1, 1);
    dim3 block(256, 1, 1);
    depen_kernel<<<grid, block, 0, stream>>>(key, qry, out1, out2);
}